// Round 6
// baseline (845.685 us; speedup 1.0000x reference)
//
#include <hip/hip_runtime.h>
#include <hip/hip_cooperative_groups.h>
#include <hip/hip_bf16.h>
#include <cstdint>

namespace cg = cooperative_groups;

// GraphSAGE 3-layer + edge predictor — single cooperative mega-kernel.
// Identities: segsum(concat(h[src],e)@Wm.T+bm,dst) = segsum(ph[src]) + pe,
//   ph = h@Wmh.T (commutes past segsum), pe = eagg@Wme.T + deg*bm,
//   eagg/deg layer-independent. ph bf16-hi (3.2MB, L2-resident gather table).
// MFMA 16x16x32 bf16 with hi/lo split (3 MFMA, err ~2^-17); A and W packed
// with the SAME (lane,elem)->k map. Phases separated by grid.sync();
// apply_l + proj_{l+1} fused per 32-row block through LDS.

#define NN 10000
#define NE 320000
#define MTB 313  // cdiv(NN,32)

typedef __attribute__((ext_vector_type(8))) short bf16x8;
typedef __attribute__((ext_vector_type(4))) float f32x4;

__device__ __forceinline__ ushort f2bf(float x) {
  union { float f; unsigned u; } c; c.f = x;
  unsigned r = c.u + 0x7FFFu + ((c.u >> 16) & 1u);
  return (ushort)(r >> 16);
}
__device__ __forceinline__ float bf2f(unsigned h) {
  union { unsigned u; float f; } c; c.u = h << 16;
  return c.f;
}
__device__ __forceinline__ f32x4 mfma3(bf16x8 ah, bf16x8 al, bf16x8 bh, bf16x8 bl,
                                       f32x4 acc) {
  acc = __builtin_amdgcn_mfma_f32_16x16x32_bf16(ah, bh, acc, 0, 0, 0);
  acc = __builtin_amdgcn_mfma_f32_16x16x32_bf16(al, bh, acc, 0, 0, 0);
  acc = __builtin_amdgcn_mfma_f32_16x16x32_bf16(ah, bl, acc, 0, 0, 0);
  return acc;
}

struct Params {
  const float *nfeats, *efeats;
  const int *src, *dst;
  const float *Wm1, *bm1, *Wa1, *ba1, *Wm2, *bm2, *Wa2, *ba2;
  const float *Wm3, *bm3, *Wa3, *ba3, *Wp, *bp;
  float* out;
  int *cnt, *fill, *offs, *ce, *cs;
  float *deg, *pe1, *pe2, *pe3, *hsd;
  ushort *nfh, *nfl, *eah, *eal, *h1h, *h1l, *h2h, *h2l, *h3h, *h3l;
  ushort *nmh, *nml, *ph;
  ushort *Wm1h, *Wm1l, *Wa1h, *Wa1l, *Wm2h, *Wm2l, *Wa2h, *Wa2l;
  ushort *Wm3h, *Wm3l, *Wa3h, *Wa3l, *Wpph, *Wppl;
};

// ---- weight pack: fp32 W[dout][Korig] -> bf16 hi/lo fragment planes ----
__device__ void prep_pack(int gtid, int NTH, const float* W, ushort* hi, ushort* lo,
                          int dout, int KA, int KApad, int KB, int Korig,
                          int NG16, int KT, int pred) {
  const int sz = KT * NG16 * 64;
  for (int tid = gtid; tid < sz; tid += NTH) {
    int lane = tid & 63;
    int g = (tid >> 6) % NG16;
    int t = (tid >> 6) / NG16;
    int col = g * 16 + (lane & 15);
    int kbase = t * 32 + ((lane >> 4) * 8);
    size_t o = (size_t)tid * 8;
#pragma unroll
    for (int j = 0; j < 8; ++j) {
      int kk = kbase + j;
      float w = 0.f;
      if (!pred) {
        if (col < dout) {
          if (kk < KApad) { if (kk < KA) w = W[(size_t)col * Korig + kk]; }
          else { int kb = kk - KApad; if (kb < KB) w = W[(size_t)col * Korig + KA + kb]; }
        }
      } else {
        if (col < 15) w = W[(size_t)col * 256 + kk];
        else if (col < 30) w = W[(size_t)(col - 15) * 256 + 128 + kk];
      }
      ushort h = f2bf(w);
      hi[o + j] = h;
      lo[o + j] = f2bf(w - bf2f(h));
    }
  }
}

// ---- gather: nm = (segsum(ph[src]) + pe)/max(deg,1), hi/lo out ----
template <int WP>
__device__ void gath_all(int gwave, int NWAVE, int lane, const ushort* ph,
                         const float* pe, const float* deg, const int* cs,
                         const int* offs, ushort* nmh, ushort* nml) {
  constexpr int PAIRS = WP / 2;
  constexpr int NV = (PAIRS + 63) / 64;
  for (int d = gwave; d < NN; d += NWAVE) {
    const int s = offs[d], t = offs[d + 1];
    float2 acc[NV][4];
#pragma unroll
    for (int v = 0; v < NV; ++v)
#pragma unroll
      for (int u = 0; u < 4; ++u) acc[v][u] = make_float2(0.f, 0.f);
    int j = s;
    for (; j + 3 < t; j += 4) {
      int s0 = cs[j], s1 = cs[j + 1], s2 = cs[j + 2], s3 = cs[j + 3];
#pragma unroll
      for (int v = 0; v < NV; ++v) {
        int p = lane + 64 * v;
        if (p < PAIRS) {
          unsigned x0 = *(const unsigned*)(ph + (size_t)s0 * WP + 2 * p);
          unsigned x1 = *(const unsigned*)(ph + (size_t)s1 * WP + 2 * p);
          unsigned x2 = *(const unsigned*)(ph + (size_t)s2 * WP + 2 * p);
          unsigned x3 = *(const unsigned*)(ph + (size_t)s3 * WP + 2 * p);
          acc[v][0].x += bf2f(x0 & 0xffffu); acc[v][0].y += bf2f(x0 >> 16);
          acc[v][1].x += bf2f(x1 & 0xffffu); acc[v][1].y += bf2f(x1 >> 16);
          acc[v][2].x += bf2f(x2 & 0xffffu); acc[v][2].y += bf2f(x2 >> 16);
          acc[v][3].x += bf2f(x3 & 0xffffu); acc[v][3].y += bf2f(x3 >> 16);
        }
      }
    }
    for (; j < t; ++j) {
      int s0 = cs[j];
#pragma unroll
      for (int v = 0; v < NV; ++v) {
        int p = lane + 64 * v;
        if (p < PAIRS) {
          unsigned x0 = *(const unsigned*)(ph + (size_t)s0 * WP + 2 * p);
          acc[v][0].x += bf2f(x0 & 0xffffu); acc[v][0].y += bf2f(x0 >> 16);
        }
      }
    }
    const float inv = 1.f / fmaxf(deg[d], 1.f);
#pragma unroll
    for (int v = 0; v < NV; ++v) {
      int p = lane + 64 * v;
      if (p < PAIRS) {
        float sx = (acc[v][0].x + acc[v][1].x) + (acc[v][2].x + acc[v][3].x);
        float sy = (acc[v][0].y + acc[v][1].y) + (acc[v][2].y + acc[v][3].y);
        float2 pv = *(const float2*)(pe + (size_t)d * WP + 2 * p);
        float nx = (sx + pv.x) * inv, ny = (sy + pv.y) * inv;
        size_t o = (size_t)d * WP + 2 * p;
        ushort hx = f2bf(nx), hy = f2bf(ny);
        *(unsigned*)(nmh + o) = (unsigned)hx | ((unsigned)hy << 16);
        *(unsigned*)(nml + o) =
            (unsigned)f2bf(nx - bf2f(hx)) | ((unsigned)f2bf(ny - bf2f(hy)) << 16);
      }
    }
  }
}

// ---- fused apply_l (A|nm)@Wa -> relu -> h planes + LDS, then proj_{l+1} ----
template <int KTH, int KTNM, int NGA, int NGP, bool PRED>
__device__ void apply_proj(const Params& P, ushort* lds,
                           const ushort* Ahi, const ushort* Alo,
                           const ushort* Wah, const ushort* Wal, const float* ba,
                           ushort* Yhi, ushort* Ylo,
                           const ushort* Wnh, const ushort* Wnl,
                           int dout_a, int dout_p, int bid, int nblk, int wid,
                           int lane) {
  constexpr int KTO = NGA / 2;       // output k-tiles (h_l width/32)
  constexpr int OSTR = KTO * 32;
  constexpr int SA = KTH * 32, SB = KTNM * 32;
  constexpr int OSTR2 = NGP * 16;
  const int rA = lane & 15, kl = (lane >> 4) * 8, colL = lane & 15;
  const int q = lane >> 4;
  for (int rb = bid; rb < MTB; rb += nblk) {
    const int row0 = rb * 32;
    const int r0 = min(row0 + rA, NN - 1), r1 = min(row0 + 16 + rA, NN - 1);
    for (int p = wid; p < NGA / 2; p += 4) {
      const int ng0 = p * 2;
      f32x4 a00 = {0.f, 0.f, 0.f, 0.f}, a01 = {0.f, 0.f, 0.f, 0.f};
      f32x4 a10 = {0.f, 0.f, 0.f, 0.f}, a11 = {0.f, 0.f, 0.f, 0.f};
#pragma unroll
      for (int kt = 0; kt < KTH + KTNM; ++kt) {
        bf16x8 a0h, a0l, a1h, a1l;
        if (kt < KTH) {
          size_t o0 = (size_t)r0 * SA + kt * 32 + kl;
          size_t o1 = (size_t)r1 * SA + kt * 32 + kl;
          a0h = *(const bf16x8*)(Ahi + o0); a0l = *(const bf16x8*)(Alo + o0);
          a1h = *(const bf16x8*)(Ahi + o1); a1l = *(const bf16x8*)(Alo + o1);
        } else {
          int kb = (kt - KTH) * 32 + kl;
          size_t o0 = (size_t)r0 * SB + kb, o1 = (size_t)r1 * SB + kb;
          a0h = *(const bf16x8*)(P.nmh + o0); a0l = *(const bf16x8*)(P.nml + o0);
          a1h = *(const bf16x8*)(P.nmh + o1); a1l = *(const bf16x8*)(P.nml + o1);
        }
        size_t wb = ((size_t)(kt * NGA + ng0) * 64 + lane) * 8;
        bf16x8 b0h = *(const bf16x8*)(Wah + wb), b0l = *(const bf16x8*)(Wal + wb);
        bf16x8 b1h = *(const bf16x8*)(Wah + wb + 512), b1l = *(const bf16x8*)(Wal + wb + 512);
        a00 = mfma3(a0h, a0l, b0h, b0l, a00);
        a01 = mfma3(a0h, a0l, b1h, b1l, a01);
        a10 = mfma3(a1h, a1l, b0h, b0l, a10);
        a11 = mfma3(a1h, a1l, b1h, b1l, a11);
      }
#pragma unroll
      for (int ms = 0; ms < 2; ++ms) {
        const f32x4 aN0 = ms ? a10 : a00;
        const f32x4 aN1 = ms ? a11 : a01;
#pragma unroll
        for (int reg = 0; reg < 4; ++reg) {
          int rloc = ms * 16 + (lane >> 4) * 4 + reg;
          int row = row0 + rloc;
#pragma unroll
          for (int ns = 0; ns < 2; ++ns) {
            int col = (ng0 + ns) * 16 + colL;
            float v = ns ? aN1[reg] : aN0[reg];
            float y = (col < dout_a) ? fmaxf(v + ba[col], 0.f) : 0.f;
            ushort h = f2bf(y), l = f2bf(y - bf2f(h));
            int idx = ((col >> 5) * 4 + ((col >> 3) & 3)) * 256 + rloc * 8 + (col & 7);
            lds[idx] = h;
            lds[idx + KTO * 1024] = l;
            if (row < NN) {
              Yhi[(size_t)row * OSTR + col] = h;
              Ylo[(size_t)row * OSTR + col] = l;
            }
          }
        }
      }
    }
    __syncthreads();
    for (int p = wid; p < NGP / 2; p += 4) {
      const int ng0 = p * 2;
      f32x4 a00 = {0.f, 0.f, 0.f, 0.f}, a01 = {0.f, 0.f, 0.f, 0.f};
      f32x4 a10 = {0.f, 0.f, 0.f, 0.f}, a11 = {0.f, 0.f, 0.f, 0.f};
#pragma unroll
      for (int kt = 0; kt < KTO; ++kt) {
        int b0 = (kt * 4 + q) * 256;
        int b1 = ((KTO + kt) * 4 + q) * 256;
        bf16x8 a0h = *(const bf16x8*)(lds + b0 + rA * 8);
        bf16x8 a1h = *(const bf16x8*)(lds + b0 + (rA + 16) * 8);
        bf16x8 a0l = *(const bf16x8*)(lds + b1 + rA * 8);
        bf16x8 a1l = *(const bf16x8*)(lds + b1 + (rA + 16) * 8);
        size_t wb = ((size_t)(kt * NGP + ng0) * 64 + lane) * 8;
        bf16x8 b0h = *(const bf16x8*)(Wnh + wb), b0l = *(const bf16x8*)(Wnl + wb);
        bf16x8 b1h = *(const bf16x8*)(Wnh + wb + 512), b1l = *(const bf16x8*)(Wnl + wb + 512);
        a00 = mfma3(a0h, a0l, b0h, b0l, a00);
        a01 = mfma3(a0h, a0l, b1h, b1l, a01);
        a10 = mfma3(a1h, a1l, b0h, b0l, a10);
        a11 = mfma3(a1h, a1l, b1h, b1l, a11);
      }
#pragma unroll
      for (int ms = 0; ms < 2; ++ms) {
        const f32x4 aN0 = ms ? a10 : a00;
        const f32x4 aN1 = ms ? a11 : a01;
#pragma unroll
        for (int reg = 0; reg < 4; ++reg) {
          int row = row0 + ms * 16 + (lane >> 4) * 4 + reg;
          if (row >= NN) continue;
#pragma unroll
          for (int ns = 0; ns < 2; ++ns) {
            int col = (ng0 + ns) * 16 + colL;
            float v = ns ? aN1[reg] : aN0[reg];
            if constexpr (PRED)
              P.hsd[(size_t)row * 32 + col] = v;
            else
              P.ph[(size_t)row * OSTR2 + col] = f2bf(col < dout_p ? v : 0.f);
          }
        }
      }
    }
    __syncthreads();
  }
}

// ---------------- the mega-kernel ----------------
__global__ __launch_bounds__(256, 2) void k_mega(Params P) {
  cg::grid_group grid = cg::this_grid();
  __shared__ ushort s_lds[10240];  // 20 KB: max 2*KTO*1024 (KTO=5)
  const int tid = threadIdx.x;
  const int bid = blockIdx.x;
  const int nblk = gridDim.x;
  const int NTH = nblk * 256;
  const int gtid = bid * 256 + tid;
  const int gwave = gtid >> 6;
  const int NWAVE = NTH >> 6;
  const int wid = tid >> 6, lane = tid & 63;

  // ---- P0: zero cnt/fill, pack weights, nf fp32 -> hi/lo ----
  for (int i = gtid; i < 2 * NN; i += NTH) P.cnt[i] = 0;
  prep_pack(gtid, NTH, P.Wm1, P.Wm1h, P.Wm1l, 152, 128, 128, 128, 256, 10, 8, 0);
  prep_pack(gtid, NTH, P.Wa1, P.Wa1h, P.Wa1l, 152, 128, 128, 152, 280, 10, 9, 0);
  prep_pack(gtid, NTH, P.Wm2, P.Wm2h, P.Wm2l, 152, 152, 160, 128, 280, 10, 9, 0);
  prep_pack(gtid, NTH, P.Wa2, P.Wa2h, P.Wa2l, 152, 152, 160, 152, 304, 10, 10, 0);
  prep_pack(gtid, NTH, P.Wm3, P.Wm3h, P.Wm3l, 128, 152, 160, 128, 280, 8, 9, 0);
  prep_pack(gtid, NTH, P.Wa3, P.Wa3h, P.Wa3l, 128, 152, 160, 128, 280, 8, 9, 0);
  prep_pack(gtid, NTH, P.Wp, P.Wpph, P.Wppl, 32, 128, 128, 0, 256, 2, 4, 1);
  for (int i = gtid; i < NN * 32; i += NTH) {  // N*128/4 float4s
    float4 v = ((const float4*)P.nfeats)[i];
    ushort h0 = f2bf(v.x), h1 = f2bf(v.y), h2 = f2bf(v.z), h3 = f2bf(v.w);
    uint2 uh, ul;
    uh.x = (unsigned)h0 | ((unsigned)h1 << 16);
    uh.y = (unsigned)h2 | ((unsigned)h3 << 16);
    ul.x = (unsigned)f2bf(v.x - bf2f(h0)) | ((unsigned)f2bf(v.y - bf2f(h1)) << 16);
    ul.y = (unsigned)f2bf(v.z - bf2f(h2)) | ((unsigned)f2bf(v.w - bf2f(h3)) << 16);
    ((uint2*)P.nfh)[i] = uh;
    ((uint2*)P.nfl)[i] = ul;
  }
  grid.sync();

  // ---- P1: histogram ----
  for (int e = gtid; e < NE; e += NTH) atomicAdd(&P.cnt[P.dst[e]], 1);
  grid.sync();

  // ---- P2: scan (block 0) ----
  if (bid == 0) {
    int* sm = (int*)s_lds;
    int c[40];
    int s = 0;
#pragma unroll
    for (int i = 0; i < 40; ++i) {
      int idx = tid * 40 + i;
      int v = (idx < NN) ? P.cnt[idx] : 0;
      s += v;
      c[i] = s;
    }
    sm[tid] = s;
    __syncthreads();
    for (int ofs = 1; ofs < 256; ofs <<= 1) {
      int add = (tid >= ofs) ? sm[tid - ofs] : 0;
      __syncthreads();
      sm[tid] += add;
      __syncthreads();
    }
    int excl = sm[tid] - s;
    if (tid == 0) P.offs[0] = 0;
#pragma unroll
    for (int i = 0; i < 40; ++i) {
      int idx = tid * 40 + i;
      if (idx < NN) P.offs[idx + 1] = excl + c[i];
    }
  }
  grid.sync();

  // ---- P3: scatter + deg ----
  for (int e = gtid; e < NE; e += NTH) {
    int d = P.dst[e];
    int pos = P.offs[d] + atomicAdd(&P.fill[d], 1);
    P.ce[pos] = e;
    P.cs[pos] = P.src[e];
  }
  for (int i = gtid; i < NN; i += NTH) P.deg[i] = (float)P.cnt[i];
  grid.sync();

  // ---- P4: eagg (HBM stream) + proj1 ----
  for (int d = gwave; d < NN; d += NWAVE) {
    int s = P.offs[d], t = P.offs[d + 1];
    float2 a0 = make_float2(0.f, 0.f), a1 = a0, a2 = a0, a3 = a0;
    int j = s;
    for (; j + 3 < t; j += 4) {
      int e0 = P.ce[j], e1 = P.ce[j + 1], e2 = P.ce[j + 2], e3 = P.ce[j + 3];
      float2 v0 = *(const float2*)(P.efeats + (size_t)e0 * 128 + lane * 2);
      float2 v1 = *(const float2*)(P.efeats + (size_t)e1 * 128 + lane * 2);
      float2 v2 = *(const float2*)(P.efeats + (size_t)e2 * 128 + lane * 2);
      float2 v3 = *(const float2*)(P.efeats + (size_t)e3 * 128 + lane * 2);
      a0.x += v0.x; a0.y += v0.y;
      a1.x += v1.x; a1.y += v1.y;
      a2.x += v2.x; a2.y += v2.y;
      a3.x += v3.x; a3.y += v3.y;
    }
    for (; j < t; ++j) {
      int e0 = P.ce[j];
      float2 v0 = *(const float2*)(P.efeats + (size_t)e0 * 128 + lane * 2);
      a0.x += v0.x; a0.y += v0.y;
    }
    float sx = (a0.x + a1.x) + (a2.x + a3.x);
    float sy = (a0.y + a1.y) + (a2.y + a3.y);
    size_t o = (size_t)d * 128 + lane * 2;
    ushort hx = f2bf(sx), hy = f2bf(sy);
    P.eah[o] = hx; P.eah[o + 1] = hy;
    P.eal[o] = f2bf(sx - bf2f(hx)); P.eal[o + 1] = f2bf(sy - bf2f(hy));
  }
  {  // proj1: ph = nf @ Wm1(h-part), bf16-hi out, 160-wide zero-padded
    const int rA = lane & 15, kl = (lane >> 4) * 8, colL = lane & 15;
    for (int t = gwave; t < 5 * MTB; t += NWAVE) {
      int ng0 = (t % 5) * 2, row0 = (t / 5) * 32;
      int r0 = min(row0 + rA, NN - 1), r1 = min(row0 + 16 + rA, NN - 1);
      f32x4 a00 = {0.f, 0.f, 0.f, 0.f}, a01 = {0.f, 0.f, 0.f, 0.f};
      f32x4 a10 = {0.f, 0.f, 0.f, 0.f}, a11 = {0.f, 0.f, 0.f, 0.f};
#pragma unroll
      for (int kt = 0; kt < 4; ++kt) {
        size_t o0 = (size_t)r0 * 128 + kt * 32 + kl;
        size_t o1 = (size_t)r1 * 128 + kt * 32 + kl;
        bf16x8 a0h = *(const bf16x8*)(P.nfh + o0), a0l = *(const bf16x8*)(P.nfl + o0);
        bf16x8 a1h = *(const bf16x8*)(P.nfh + o1), a1l = *(const bf16x8*)(P.nfl + o1);
        size_t wb = ((size_t)(kt * 10 + ng0) * 64 + lane) * 8;
        bf16x8 b0h = *(const bf16x8*)(P.Wm1h + wb), b0l = *(const bf16x8*)(P.Wm1l + wb);
        bf16x8 b1h = *(const bf16x8*)(P.Wm1h + wb + 512), b1l = *(const bf16x8*)(P.Wm1l + wb + 512);
        a00 = mfma3(a0h, a0l, b0h, b0l, a00);
        a01 = mfma3(a0h, a0l, b1h, b1l, a01);
        a10 = mfma3(a1h, a1l, b0h, b0l, a10);
        a11 = mfma3(a1h, a1l, b1h, b1l, a11);
      }
#pragma unroll
      for (int ms = 0; ms < 2; ++ms) {
        const f32x4 aN0 = ms ? a10 : a00;
        const f32x4 aN1 = ms ? a11 : a01;
#pragma unroll
        for (int reg = 0; reg < 4; ++reg) {
          int row = row0 + ms * 16 + (lane >> 4) * 4 + reg;
          if (row >= NN) continue;
#pragma unroll
          for (int ns = 0; ns < 2; ++ns) {
            int col = (ng0 + ns) * 16 + colL;
            float v = ns ? aN1[reg] : aN0[reg];
            P.ph[(size_t)row * 160 + col] = f2bf(col < 152 ? v : 0.f);
          }
        }
      }
    }
  }
  grid.sync();

  // ---- P5: pe_l = eagg @ Wme_l + deg*bm_l (3 layers, flattened tiles) ----
  {
    const int rA = lane & 15, kl = (lane >> 4) * 8, colL = lane & 15;
    for (int t = gwave; t < 14 * MTB; t += NWAVE) {
      int l, bx, by;
      if (t < 5 * MTB) { l = 0; bx = t % 5; by = t / 5; }
      else if (t < 10 * MTB) { l = 1; int tt = t - 5 * MTB; bx = tt % 5; by = tt / 5; }
      else { l = 2; int tt = t - 10 * MTB; bx = tt % 4; by = tt / 4; }
      const ushort* Wh; const ushort* Wl; const float* bm; float* pe;
      int NG16, WPAD, dout;
      if (l == 0) { Wh = P.Wm1h + (size_t)4 * 10 * 512; Wl = P.Wm1l + (size_t)4 * 10 * 512;
                    bm = P.bm1; pe = P.pe1; NG16 = 10; WPAD = 160; dout = 152; }
      else if (l == 1) { Wh = P.Wm2h + (size_t)5 * 10 * 512; Wl = P.Wm2l + (size_t)5 * 10 * 512;
                         bm = P.bm2; pe = P.pe2; NG16 = 10; WPAD = 160; dout = 152; }
      else { Wh = P.Wm3h + (size_t)5 * 8 * 512; Wl = P.Wm3l + (size_t)5 * 8 * 512;
             bm = P.bm3; pe = P.pe3; NG16 = 8; WPAD = 128; dout = 128; }
      int ng0 = bx * 2, row0 = by * 32;
      int r0 = min(row0 + rA, NN - 1), r1 = min(row0 + 16 + rA, NN - 1);
      f32x4 a00 = {0.f, 0.f, 0.f, 0.f}, a01 = {0.f, 0.f, 0.f, 0.f};
      f32x4 a10 = {0.f, 0.f, 0.f, 0.f}, a11 = {0.f, 0.f, 0.f, 0.f};
#pragma unroll
      for (int kt = 0; kt < 4; ++kt) {
        size_t o0 = (size_t)r0 * 128 + kt * 32 + kl;
        size_t o1 = (size_t)r1 * 128 + kt * 32 + kl;
        bf16x8 a0h = *(const bf16x8*)(P.eah + o0), a0l = *(const bf16x8*)(P.eal + o0);
        bf16x8 a1h = *(const bf16x8*)(P.eah + o1), a1l = *(const bf16x8*)(P.eal + o1);
        size_t wb = ((size_t)(kt * NG16 + ng0) * 64 + lane) * 8;
        bf16x8 b0h = *(const bf16x8*)(Wh + wb), b0l = *(const bf16x8*)(Wl + wb);
        bf16x8 b1h = *(const bf16x8*)(Wh + wb + 512), b1l = *(const bf16x8*)(Wl + wb + 512);
        a00 = mfma3(a0h, a0l, b0h, b0l, a00);
        a01 = mfma3(a0h, a0l, b1h, b1l, a01);
        a10 = mfma3(a1h, a1l, b0h, b0l, a10);
        a11 = mfma3(a1h, a1l, b1h, b1l, a11);
      }
#pragma unroll
      for (int ms = 0; ms < 2; ++ms) {
        const f32x4 aN0 = ms ? a10 : a00;
        const f32x4 aN1 = ms ? a11 : a01;
#pragma unroll
        for (int reg = 0; reg < 4; ++reg) {
          int row = row0 + ms * 16 + (lane >> 4) * 4 + reg;
          if (row >= NN) continue;
          float dg = P.deg[row];
#pragma unroll
          for (int ns = 0; ns < 2; ++ns) {
            int col = (ng0 + ns) * 16 + colL;
            float v = ns ? aN1[reg] : aN0[reg];
            pe[(size_t)row * WPAD + col] = (col < dout) ? v + dg * bm[col] : 0.f;
          }
        }
      }
    }
  }
  grid.sync();

  // ---- P6: gather1; P7: apply1+proj2; P8..P11; P12: edge_out ----
  gath_all<160>(gwave, NWAVE, lane, P.ph, P.pe1, P.deg, P.cs, P.offs, P.nmh, P.nml);
  grid.sync();
  apply_proj<4, 5, 10, 10, false>(P, s_lds, P.nfh, P.nfl, P.Wa1h, P.Wa1l, P.ba1,
                                  P.h1h, P.h1l, P.Wm2h, P.Wm2l, 152, 152, bid, nblk, wid, lane);
  grid.sync();
  gath_all<160>(gwave, NWAVE, lane, P.ph, P.pe2, P.deg, P.cs, P.offs, P.nmh, P.nml);
  grid.sync();
  apply_proj<5, 5, 10, 8, false>(P, s_lds, P.h1h, P.h1l, P.Wa2h, P.Wa2l, P.ba2,
                                 P.h2h, P.h2l, P.Wm3h, P.Wm3l, 152, 128, bid, nblk, wid, lane);
  grid.sync();
  gath_all<128>(gwave, NWAVE, lane, P.ph, P.pe3, P.deg, P.cs, P.offs, P.nmh, P.nml);
  grid.sync();
  apply_proj<5, 4, 8, 2, true>(P, s_lds, P.h2h, P.h2l, P.Wa3h, P.Wa3l, P.ba3,
                               P.h3h, P.h3l, P.Wpph, P.Wppl, 128, 32, bid, nblk, wid, lane);
  grid.sync();
  for (int i = gtid; i < NE * 15; i += NTH) {
    int e = i / 15, c = i - e * 15;
    P.out[i] = P.hsd[(size_t)P.src[e] * 32 + c] + P.hsd[(size_t)P.dst[e] * 32 + 15 + c] + P.bp[c];
  }
}

extern "C" void kernel_launch(void* const* d_in, const int* in_sizes, int n_in,
                              void* d_out, int out_size, void* d_ws, size_t ws_size,
                              hipStream_t stream) {
  Params P;
  P.nfeats = (const float*)d_in[0];
  P.efeats = (const float*)d_in[1];
  P.src = (const int*)d_in[2];
  P.dst = (const int*)d_in[3];
  P.Wm1 = (const float*)d_in[4];  P.bm1 = (const float*)d_in[5];
  P.Wa1 = (const float*)d_in[6];  P.ba1 = (const float*)d_in[7];
  P.Wm2 = (const float*)d_in[8];  P.bm2 = (const float*)d_in[9];
  P.Wa2 = (const float*)d_in[10]; P.ba2 = (const float*)d_in[11];
  P.Wm3 = (const float*)d_in[12]; P.bm3 = (const float*)d_in[13];
  P.Wa3 = (const float*)d_in[14]; P.ba3 = (const float*)d_in[15];
  P.Wp = (const float*)d_in[16];  P.bp = (const float*)d_in[17];
  P.out = (float*)d_out;

  char* base = (char*)d_ws;
  size_t woff = 0;
  auto alloc = [&](size_t bytes) -> void* {
    void* p = base + woff;
    woff += (bytes + 255) & ~(size_t)255;
    return p;
  };
  P.cnt = (int*)alloc((size_t)2 * NN * 4);
  P.fill = P.cnt + NN;
  P.offs = (int*)alloc((size_t)(NN + 1) * 4);
  P.ce = (int*)alloc((size_t)NE * 4);
  P.cs = (int*)alloc((size_t)NE * 4);
  P.deg = (float*)alloc((size_t)NN * 4);
  auto aplane = [&](int w) { return (ushort*)alloc((size_t)NN * w * 2); };
  P.nfh = aplane(128); P.nfl = aplane(128);
  P.eah = aplane(128); P.eal = aplane(128);
  P.h1h = aplane(160); P.h1l = aplane(160);
  P.h2h = aplane(160); P.h2l = aplane(160);
  P.h3h = aplane(128); P.h3l = aplane(128);
  P.nmh = aplane(160); P.nml = aplane(160);
  P.ph = aplane(160);
  P.pe1 = (float*)alloc((size_t)NN * 160 * 4);
  P.pe2 = (float*)alloc((size_t)NN * 160 * 4);
  P.pe3 = (float*)alloc((size_t)NN * 128 * 4);
  P.hsd = (float*)alloc((size_t)NN * 32 * 4);
  auto wpk = [&](int kt, int ng) { return (ushort*)alloc((size_t)kt * ng * 512 * 2); };
  P.Wm1h = wpk(8, 10);  P.Wm1l = wpk(8, 10);
  P.Wa1h = wpk(9, 10);  P.Wa1l = wpk(9, 10);
  P.Wm2h = wpk(9, 10);  P.Wm2l = wpk(9, 10);
  P.Wa2h = wpk(10, 10); P.Wa2l = wpk(10, 10);
  P.Wm3h = wpk(9, 8);   P.Wm3l = wpk(9, 8);
  P.Wa3h = wpk(9, 8);   P.Wa3l = wpk(9, 8);
  P.Wpph = wpk(4, 2);   P.Wppl = wpk(4, 2);

  int maxb = 0;
  hipOccupancyMaxActiveBlocksPerMultiprocessor(&maxb, k_mega, 256, 0);
  if (maxb < 1) maxb = 1;
  int grid = maxb * 256;  // 256 CUs
  if (grid > 512) grid = 512;
  void* args[] = {(void*)&P};
  hipLaunchCooperativeKernel((void*)k_mega, dim3(grid), dim3(256), args, 0, stream);
}

// Round 7
// 240.231 us; speedup vs baseline: 3.5203x; 3.5203x over previous
//
#include <hip/hip_runtime.h>
#include <hip/hip_bf16.h>
#include <cstdint>

// GraphSAGE 3-layer + edge predictor. Multi-kernel (R5 structure) with
// block-local fusions proven in R6:
//   segsum(concat(h[src],e)@Wm.T+bm,dst) = segsum(ph[src]) + pe
//     ph = h@Wmh.T (commutes past segsum), pe = eagg@Wme.T + deg*bm
//   eagg/deg layer-independent. ph bf16-hi (3.2MB, L2-resident gather table).
// Fusions: apply_l+proj_{l+1} per 32-row block via LDS; proj1+pe{1,2,3} in one
// dispatch; W-pack + nf-split in one dispatch. MFMA 16x16x32 bf16, hi/lo split
// (3 MFMA, err ~2^-17); A and W packed with the SAME (lane,elem)->k map.

static inline int cdiv(int a, int b) { return (a + b - 1) / b; }

#define NN 10000
#define NE 320000
#define MTB 313  // cdiv(NN,32)

typedef __attribute__((ext_vector_type(8))) short bf16x8;
typedef __attribute__((ext_vector_type(4))) float f32x4;

__device__ __forceinline__ ushort f2bf(float x) {
  union { float f; unsigned u; } c; c.f = x;
  unsigned r = c.u + 0x7FFFu + ((c.u >> 16) & 1u);
  return (ushort)(r >> 16);
}
__device__ __forceinline__ float bf2f(unsigned h) {
  union { unsigned u; float f; } c; c.u = h << 16;
  return c.f;
}
__device__ __forceinline__ f32x4 mfma3(bf16x8 ah, bf16x8 al, bf16x8 bh, bf16x8 bl,
                                       f32x4 acc) {
  acc = __builtin_amdgcn_mfma_f32_16x16x32_bf16(ah, bh, acc, 0, 0, 0);
  acc = __builtin_amdgcn_mfma_f32_16x16x32_bf16(al, bh, acc, 0, 0, 0);
  acc = __builtin_amdgcn_mfma_f32_16x16x32_bf16(ah, bl, acc, 0, 0, 0);
  return acc;
}

// ---------------- CSR build ----------------
__global__ __launch_bounds__(256) void k_hist(const int* __restrict__ dst,
                                              int* __restrict__ cnt) {
  int e = blockIdx.x * 256 + threadIdx.x;
  if (e < NE) atomicAdd(&cnt[dst[e]], 1);
}

__global__ __launch_bounds__(1024) void k_scan(const int* __restrict__ cnt,
                                               int* __restrict__ offs) {
  __shared__ int smem[1024];
  const int t = threadIdx.x;
  const int base = t * 10;
  int c[10];
  int s = 0;
#pragma unroll
  for (int i = 0; i < 10; ++i) {
    int idx = base + i;
    int v = (idx < NN) ? cnt[idx] : 0;
    s += v;
    c[i] = s;
  }
  smem[t] = s;
  __syncthreads();
  for (int ofs = 1; ofs < 1024; ofs <<= 1) {
    int add = (t >= ofs) ? smem[t - ofs] : 0;
    __syncthreads();
    smem[t] += add;
    __syncthreads();
  }
  int excl = smem[t] - s;
  if (t == 0) offs[0] = 0;
#pragma unroll
  for (int i = 0; i < 10; ++i) {
    int idx = base + i;
    if (idx < NN) offs[idx + 1] = excl + c[i];
  }
}

__global__ __launch_bounds__(256) void k_scatter(const int* __restrict__ src,
                                                 const int* __restrict__ dst,
                                                 const int* __restrict__ offs,
                                                 int* __restrict__ fill,
                                                 int* __restrict__ csr_edge,
                                                 int* __restrict__ csr_src) {
  int e = blockIdx.x * 256 + threadIdx.x;
  if (e < NE) {
    int d = dst[e];
    int pos = offs[d] + atomicAdd(&fill[d], 1);
    csr_edge[pos] = e;
    csr_src[pos] = src[e];
  }
}

// ---------------- prep: W packs (y<7) + nf fp32->hi/lo (y==7) ----------------
struct WDesc {
  const float* W; ushort* hi; ushort* lo;
  int dout, KA, KApad, KB, Korig, NG16, KT, pred;
};
struct PrepArgs {
  WDesc d[7];
  const float* nf; ushort* nfh; ushort* nfl;
};

__global__ __launch_bounds__(256) void k_prep(PrepArgs P) {
  const int y = blockIdx.y;
  if (y == 7) {  // nf conversion: N*32 float4s
    const int NTH = gridDim.x * 256;
    for (int i = blockIdx.x * 256 + threadIdx.x; i < NN * 32; i += NTH) {
      float4 v = ((const float4*)P.nf)[i];
      ushort h0 = f2bf(v.x), h1 = f2bf(v.y), h2 = f2bf(v.z), h3 = f2bf(v.w);
      uint2 uh, ul;
      uh.x = (unsigned)h0 | ((unsigned)h1 << 16);
      uh.y = (unsigned)h2 | ((unsigned)h3 << 16);
      ul.x = (unsigned)f2bf(v.x - bf2f(h0)) | ((unsigned)f2bf(v.y - bf2f(h1)) << 16);
      ul.y = (unsigned)f2bf(v.z - bf2f(h2)) | ((unsigned)f2bf(v.w - bf2f(h3)) << 16);
      ((uint2*)P.nfh)[i] = uh;
      ((uint2*)P.nfl)[i] = ul;
    }
    return;
  }
  const WDesc d = P.d[y];
  int tid = blockIdx.x * 256 + threadIdx.x;
  if (tid >= d.KT * d.NG16 * 64) return;
  int lane = tid & 63;
  int g = (tid >> 6) % d.NG16;
  int t = (tid >> 6) / d.NG16;
  int col = g * 16 + (lane & 15);
  int kbase = t * 32 + ((lane >> 4) * 8);
  size_t o = (size_t)tid * 8;
#pragma unroll
  for (int j = 0; j < 8; ++j) {
    int kk = kbase + j;
    float w = 0.f;
    if (!d.pred) {
      if (col < d.dout) {
        if (kk < d.KApad) { if (kk < d.KA) w = d.W[(size_t)col * d.Korig + kk]; }
        else { int kb = kk - d.KApad; if (kb < d.KB) w = d.W[(size_t)col * d.Korig + d.KA + kb]; }
      }
    } else {
      if (col < 15) w = d.W[(size_t)col * 256 + kk];
      else if (col < 30) w = d.W[(size_t)(col - 15) * 256 + 128 + kk];
    }
    ushort h = f2bf(w);
    d.hi[o + j] = h;
    d.lo[o + j] = f2bf(w - bf2f(h));
  }
}

// ---------------- edge-feature aggregation (the big HBM read) ----------------
__global__ __launch_bounds__(64) void k_eagg(const float* __restrict__ efeats,
                                             const int* __restrict__ csr_edge,
                                             const int* __restrict__ offs,
                                             ushort* __restrict__ ehi,
                                             ushort* __restrict__ elo,
                                             float* __restrict__ deg) {
  int d = blockIdx.x, lane = threadIdx.x;
  int s = offs[d], t = offs[d + 1];
  float2 a0 = make_float2(0.f, 0.f), a1 = a0, a2 = a0, a3 = a0;
  int j = s;
  for (; j + 7 < t; j += 8) {
    int e0 = csr_edge[j], e1 = csr_edge[j + 1], e2 = csr_edge[j + 2], e3 = csr_edge[j + 3];
    int e4 = csr_edge[j + 4], e5 = csr_edge[j + 5], e6 = csr_edge[j + 6], e7 = csr_edge[j + 7];
    float2 v0 = *(const float2*)(efeats + (size_t)e0 * 128 + lane * 2);
    float2 v1 = *(const float2*)(efeats + (size_t)e1 * 128 + lane * 2);
    float2 v2 = *(const float2*)(efeats + (size_t)e2 * 128 + lane * 2);
    float2 v3 = *(const float2*)(efeats + (size_t)e3 * 128 + lane * 2);
    float2 v4 = *(const float2*)(efeats + (size_t)e4 * 128 + lane * 2);
    float2 v5 = *(const float2*)(efeats + (size_t)e5 * 128 + lane * 2);
    float2 v6 = *(const float2*)(efeats + (size_t)e6 * 128 + lane * 2);
    float2 v7 = *(const float2*)(efeats + (size_t)e7 * 128 + lane * 2);
    a0.x += v0.x + v4.x; a0.y += v0.y + v4.y;
    a1.x += v1.x + v5.x; a1.y += v1.y + v5.y;
    a2.x += v2.x + v6.x; a2.y += v2.y + v6.y;
    a3.x += v3.x + v7.x; a3.y += v3.y + v7.y;
  }
  for (; j + 3 < t; j += 4) {
    int e0 = csr_edge[j], e1 = csr_edge[j + 1], e2 = csr_edge[j + 2], e3 = csr_edge[j + 3];
    float2 v0 = *(const float2*)(efeats + (size_t)e0 * 128 + lane * 2);
    float2 v1 = *(const float2*)(efeats + (size_t)e1 * 128 + lane * 2);
    float2 v2 = *(const float2*)(efeats + (size_t)e2 * 128 + lane * 2);
    float2 v3 = *(const float2*)(efeats + (size_t)e3 * 128 + lane * 2);
    a0.x += v0.x; a0.y += v0.y;
    a1.x += v1.x; a1.y += v1.y;
    a2.x += v2.x; a2.y += v2.y;
    a3.x += v3.x; a3.y += v3.y;
  }
  for (; j < t; ++j) {
    int e0 = csr_edge[j];
    float2 v0 = *(const float2*)(efeats + (size_t)e0 * 128 + lane * 2);
    a0.x += v0.x; a0.y += v0.y;
  }
  float sx = (a0.x + a1.x) + (a2.x + a3.x);
  float sy = (a0.y + a1.y) + (a2.y + a3.y);
  size_t o = (size_t)d * 128 + lane * 2;
  ushort hx = f2bf(sx), hy = f2bf(sy);
  ehi[o] = hx; ehi[o + 1] = hy;
  elo[o] = f2bf(sx - bf2f(hx)); elo[o + 1] = f2bf(sy - bf2f(hy));
  if (lane == 0) deg[d] = (float)(t - s);
}

// ---------------- proj1 + pe1/pe2/pe3 (flattened, 1 wave/block, K=4) ----------
__global__ __launch_bounds__(64) void k_projpe(
    const ushort* __restrict__ nfh, const ushort* __restrict__ nfl,
    const ushort* __restrict__ eah, const ushort* __restrict__ eal,
    const ushort* __restrict__ Wm1h, const ushort* __restrict__ Wm1l,
    const ushort* __restrict__ pW1h, const ushort* __restrict__ pW1l,
    const ushort* __restrict__ pW2h, const ushort* __restrict__ pW2l,
    const ushort* __restrict__ pW3h, const ushort* __restrict__ pW3l,
    const float* __restrict__ bm1, const float* __restrict__ bm2,
    const float* __restrict__ bm3, const float* __restrict__ deg,
    ushort* __restrict__ ph, float* __restrict__ pe1, float* __restrict__ pe2,
    float* __restrict__ pe3) {
  const int bx = blockIdx.x, lane = threadIdx.x;
  const ushort *Ah, *Al, *Wh, *Wl;
  const float* bm = nullptr;
  float* pe = nullptr;
  int NG16, ng0, WPAD = 160, dout;
  bool proj = false;
  if (bx < 5) {
    proj = true; Ah = nfh; Al = nfl; Wh = Wm1h; Wl = Wm1l;
    NG16 = 10; ng0 = bx * 2; dout = 152;
  } else if (bx < 10) {
    Ah = eah; Al = eal; Wh = pW1h; Wl = pW1l; bm = bm1; pe = pe1;
    NG16 = 10; ng0 = (bx - 5) * 2; dout = 152;
  } else if (bx < 15) {
    Ah = eah; Al = eal; Wh = pW2h; Wl = pW2l; bm = bm2; pe = pe2;
    NG16 = 10; ng0 = (bx - 10) * 2; dout = 152;
  } else {
    Ah = eah; Al = eal; Wh = pW3h; Wl = pW3l; bm = bm3; pe = pe3;
    NG16 = 8; ng0 = (bx - 15) * 2; WPAD = 128; dout = 128;
  }
  const int row0 = blockIdx.y * 32;
  const int rA = lane & 15, kl = (lane >> 4) * 8, colL = lane & 15;
  const int r0 = min(row0 + rA, NN - 1), r1 = min(row0 + 16 + rA, NN - 1);
  f32x4 a00 = {0.f, 0.f, 0.f, 0.f}, a01 = {0.f, 0.f, 0.f, 0.f};
  f32x4 a10 = {0.f, 0.f, 0.f, 0.f}, a11 = {0.f, 0.f, 0.f, 0.f};
#pragma unroll
  for (int kt = 0; kt < 4; ++kt) {
    size_t o0 = (size_t)r0 * 128 + kt * 32 + kl;
    size_t o1 = (size_t)r1 * 128 + kt * 32 + kl;
    bf16x8 a0h = *(const bf16x8*)(Ah + o0), a0l = *(const bf16x8*)(Al + o0);
    bf16x8 a1h = *(const bf16x8*)(Ah + o1), a1l = *(const bf16x8*)(Al + o1);
    size_t wb = ((size_t)(kt * NG16 + ng0) * 64 + lane) * 8;
    bf16x8 b0h = *(const bf16x8*)(Wh + wb), b0l = *(const bf16x8*)(Wl + wb);
    bf16x8 b1h = *(const bf16x8*)(Wh + wb + 512), b1l = *(const bf16x8*)(Wl + wb + 512);
    a00 = mfma3(a0h, a0l, b0h, b0l, a00);
    a01 = mfma3(a0h, a0l, b1h, b1l, a01);
    a10 = mfma3(a1h, a1l, b0h, b0l, a10);
    a11 = mfma3(a1h, a1l, b1h, b1l, a11);
  }
#pragma unroll
  for (int ms = 0; ms < 2; ++ms) {
    const f32x4 aN0 = ms ? a10 : a00;
    const f32x4 aN1 = ms ? a11 : a01;
#pragma unroll
    for (int reg = 0; reg < 4; ++reg) {
      int row = row0 + ms * 16 + (lane >> 4) * 4 + reg;
      if (row >= NN) continue;
#pragma unroll
      for (int ns = 0; ns < 2; ++ns) {
        int col = (ng0 + ns) * 16 + colL;
        float v = ns ? aN1[reg] : aN0[reg];
        if (proj) {
          ph[(size_t)row * 160 + col] = f2bf(col < 152 ? v : 0.f);
        } else {
          pe[(size_t)row * WPAD + col] = (col < dout) ? v + deg[row] * bm[col] : 0.f;
        }
      }
    }
  }
}

// ---------------- gather: nm = (segsum(ph[src]) + pe)/max(deg,1) ----------------
template <int WP>
__global__ __launch_bounds__(64) void k_gath(const ushort* __restrict__ ph,
                                             const float* __restrict__ pe,
                                             const float* __restrict__ deg,
                                             const int* __restrict__ cs,
                                             const int* __restrict__ offs,
                                             ushort* __restrict__ nmh,
                                             ushort* __restrict__ nml) {
  constexpr int PAIRS = WP / 2;
  constexpr int NV = (PAIRS + 63) / 64;
  const int d = blockIdx.x, lane = threadIdx.x;
  const int s = offs[d], t = offs[d + 1];
  float2 acc[NV][4];
#pragma unroll
  for (int v = 0; v < NV; ++v)
#pragma unroll
    for (int u = 0; u < 4; ++u) acc[v][u] = make_float2(0.f, 0.f);
  int j = s;
  for (; j + 3 < t; j += 4) {
    int s0 = cs[j], s1 = cs[j + 1], s2 = cs[j + 2], s3 = cs[j + 3];
#pragma unroll
    for (int v = 0; v < NV; ++v) {
      int p = lane + 64 * v;
      if (p < PAIRS) {
        unsigned x0 = *(const unsigned*)(ph + (size_t)s0 * WP + 2 * p);
        unsigned x1 = *(const unsigned*)(ph + (size_t)s1 * WP + 2 * p);
        unsigned x2 = *(const unsigned*)(ph + (size_t)s2 * WP + 2 * p);
        unsigned x3 = *(const unsigned*)(ph + (size_t)s3 * WP + 2 * p);
        acc[v][0].x += bf2f(x0 & 0xffffu); acc[v][0].y += bf2f(x0 >> 16);
        acc[v][1].x += bf2f(x1 & 0xffffu); acc[v][1].y += bf2f(x1 >> 16);
        acc[v][2].x += bf2f(x2 & 0xffffu); acc[v][2].y += bf2f(x2 >> 16);
        acc[v][3].x += bf2f(x3 & 0xffffu); acc[v][3].y += bf2f(x3 >> 16);
      }
    }
  }
  for (; j < t; ++j) {
    int s0 = cs[j];
#pragma unroll
    for (int v = 0; v < NV; ++v) {
      int p = lane + 64 * v;
      if (p < PAIRS) {
        unsigned x0 = *(const unsigned*)(ph + (size_t)s0 * WP + 2 * p);
        acc[v][0].x += bf2f(x0 & 0xffffu); acc[v][0].y += bf2f(x0 >> 16);
      }
    }
  }
  const float inv = 1.f / fmaxf(deg[d], 1.f);
#pragma unroll
  for (int v = 0; v < NV; ++v) {
    int p = lane + 64 * v;
    if (p < PAIRS) {
      float sx = (acc[v][0].x + acc[v][1].x) + (acc[v][2].x + acc[v][3].x);
      float sy = (acc[v][0].y + acc[v][1].y) + (acc[v][2].y + acc[v][3].y);
      float2 pv = *(const float2*)(pe + (size_t)d * WP + 2 * p);
      float nx = (sx + pv.x) * inv, ny = (sy + pv.y) * inv;
      size_t o = (size_t)d * WP + 2 * p;
      ushort hx = f2bf(nx), hy = f2bf(ny);
      *(unsigned*)(nmh + o) = (unsigned)hx | ((unsigned)hy << 16);
      *(unsigned*)(nml + o) =
          (unsigned)f2bf(nx - bf2f(hx)) | ((unsigned)f2bf(ny - bf2f(hy)) << 16);
    }
  }
}

// ---------------- fused apply_l + proj_{l+1} (per 32-row block via LDS) --------
// Part1: h_next = relu(concat(A,nm)@Wa + ba) -> LDS packed + global planes.
// Part2: ph = h_next@Wn (bf16-hi), or hsd fp32 when PRED.
template <int KTH, int KTNM, int NGA, int NGP, bool PRED>
__global__ __launch_bounds__(NGA * 32) void k_applyproj(
    const ushort* __restrict__ Ahi, const ushort* __restrict__ Alo,
    const ushort* __restrict__ nmh, const ushort* __restrict__ nml,
    const ushort* __restrict__ Wah, const ushort* __restrict__ Wal,
    const float* __restrict__ ba,
    ushort* __restrict__ Yhi, ushort* __restrict__ Ylo,
    const ushort* __restrict__ Wnh, const ushort* __restrict__ Wnl,
    ushort* __restrict__ phout, float* __restrict__ hsd,
    int dout_a, int dout_p) {
  constexpr int KTO = NGA / 2;  // h_next width / 32
  constexpr int OSTR = KTO * 32;
  constexpr int SA = KTH * 32, SB = KTNM * 32;
  constexpr int OSTR2 = NGP * 16;
  __shared__ ushort lds[2 * KTO * 1024];
  const int tid = threadIdx.x;
  const int wid = tid >> 6, lane = tid & 63;
  const int rA = lane & 15, kl = (lane >> 4) * 8, colL = lane & 15;
  const int q = lane >> 4;
  const int row0 = blockIdx.x * 32;
  const int r0 = min(row0 + rA, NN - 1), r1 = min(row0 + 16 + rA, NN - 1);
  // ---- part 1: apply ----
  {
    const int ng0 = wid * 2;
    f32x4 a00 = {0.f, 0.f, 0.f, 0.f}, a01 = {0.f, 0.f, 0.f, 0.f};
    f32x4 a10 = {0.f, 0.f, 0.f, 0.f}, a11 = {0.f, 0.f, 0.f, 0.f};
#pragma unroll
    for (int kt = 0; kt < KTH + KTNM; ++kt) {
      bf16x8 a0h, a0l, a1h, a1l;
      if (kt < KTH) {
        size_t o0 = (size_t)r0 * SA + kt * 32 + kl;
        size_t o1 = (size_t)r1 * SA + kt * 32 + kl;
        a0h = *(const bf16x8*)(Ahi + o0); a0l = *(const bf16x8*)(Alo + o0);
        a1h = *(const bf16x8*)(Ahi + o1); a1l = *(const bf16x8*)(Alo + o1);
      } else {
        int kb = (kt - KTH) * 32 + kl;
        size_t o0 = (size_t)r0 * SB + kb, o1 = (size_t)r1 * SB + kb;
        a0h = *(const bf16x8*)(nmh + o0); a0l = *(const bf16x8*)(nml + o0);
        a1h = *(const bf16x8*)(nmh + o1); a1l = *(const bf16x8*)(nml + o1);
      }
      size_t wb = ((size_t)(kt * NGA + ng0) * 64 + lane) * 8;
      bf16x8 b0h = *(const bf16x8*)(Wah + wb), b0l = *(const bf16x8*)(Wal + wb);
      bf16x8 b1h = *(const bf16x8*)(Wah + wb + 512), b1l = *(const bf16x8*)(Wal + wb + 512);
      a00 = mfma3(a0h, a0l, b0h, b0l, a00);
      a01 = mfma3(a0h, a0l, b1h, b1l, a01);
      a10 = mfma3(a1h, a1l, b0h, b0l, a10);
      a11 = mfma3(a1h, a1l, b1h, b1l, a11);
    }
#pragma unroll
    for (int ms = 0; ms < 2; ++ms) {
      const f32x4 aN0 = ms ? a10 : a00;
      const f32x4 aN1 = ms ? a11 : a01;
#pragma unroll
      for (int reg = 0; reg < 4; ++reg) {
        int rloc = ms * 16 + (lane >> 4) * 4 + reg;
        int row = row0 + rloc;
#pragma unroll
        for (int ns = 0; ns < 2; ++ns) {
          int col = (ng0 + ns) * 16 + colL;
          float v = ns ? aN1[reg] : aN0[reg];
          float y = (col < dout_a) ? fmaxf(v + ba[col], 0.f) : 0.f;
          ushort h = f2bf(y), l = f2bf(y - bf2f(h));
          int idx = ((col >> 5) * 4 + ((col >> 3) & 3)) * 256 + rloc * 8 + (col & 7);
          lds[idx] = h;
          lds[idx + KTO * 1024] = l;
          if constexpr (!PRED) {
            if (row < NN) {
              Yhi[(size_t)row * OSTR + col] = h;
              Ylo[(size_t)row * OSTR + col] = l;
            }
          }
        }
      }
    }
  }
  __syncthreads();
  // ---- part 2: proj (or pred) from LDS ----
  if (wid < NGP / 2) {
    const int ng0 = wid * 2;
    f32x4 a00 = {0.f, 0.f, 0.f, 0.f}, a01 = {0.f, 0.f, 0.f, 0.f};
    f32x4 a10 = {0.f, 0.f, 0.f, 0.f}, a11 = {0.f, 0.f, 0.f, 0.f};
#pragma unroll
    for (int kt = 0; kt < KTO; ++kt) {
      int b0 = (kt * 4 + q) * 256;
      int b1 = ((KTO + kt) * 4 + q) * 256;
      bf16x8 a0h = *(const bf16x8*)(lds + b0 + rA * 8);
      bf16x8 a1h = *(const bf16x8*)(lds + b0 + (rA + 16) * 8);
      bf16x8 a0l = *(const bf16x8*)(lds + b1 + rA * 8);
      bf16x8 a1l = *(const bf16x8*)(lds + b1 + (rA + 16) * 8);
      size_t wb = ((size_t)(kt * NGP + ng0) * 64 + lane) * 8;
      bf16x8 b0h = *(const bf16x8*)(Wnh + wb), b0l = *(const bf16x8*)(Wnl + wb);
      bf16x8 b1h = *(const bf16x8*)(Wnh + wb + 512), b1l = *(const bf16x8*)(Wnl + wb + 512);
      a00 = mfma3(a0h, a0l, b0h, b0l, a00);
      a01 = mfma3(a0h, a0l, b1h, b1l, a01);
      a10 = mfma3(a1h, a1l, b0h, b0l, a10);
      a11 = mfma3(a1h, a1l, b1h, b1l, a11);
    }
#pragma unroll
    for (int ms = 0; ms < 2; ++ms) {
      const f32x4 aN0 = ms ? a10 : a00;
      const f32x4 aN1 = ms ? a11 : a01;
#pragma unroll
      for (int reg = 0; reg < 4; ++reg) {
        int row = row0 + ms * 16 + (lane >> 4) * 4 + reg;
        if (row >= NN) continue;
#pragma unroll
        for (int ns = 0; ns < 2; ++ns) {
          int col = (ng0 + ns) * 16 + colL;
          float v = ns ? aN1[reg] : aN0[reg];
          if constexpr (PRED)
            hsd[(size_t)row * 32 + col] = v;
          else
            phout[(size_t)row * OSTR2 + col] = f2bf(col < dout_p ? v : 0.f);
        }
      }
    }
  }
}

// ---------------- edge output ----------------
__global__ __launch_bounds__(256) void k_edge_out(const int* __restrict__ src,
                                                  const int* __restrict__ dst,
                                                  const float* __restrict__ hsd,
                                                  const float* __restrict__ bp,
                                                  float* __restrict__ out) {
  int i = blockIdx.x * 256 + threadIdx.x;
  if (i >= NE * 15) return;
  int e = i / 15, c = i - e * 15;
  out[i] = hsd[(size_t)src[e] * 32 + c] + hsd[(size_t)dst[e] * 32 + 15 + c] + bp[c];
}

extern "C" void kernel_launch(void* const* d_in, const int* in_sizes, int n_in,
                              void* d_out, int out_size, void* d_ws, size_t ws_size,
                              hipStream_t stream) {
  const float* nfeats = (const float*)d_in[0];
  const float* efeats = (const float*)d_in[1];
  const int* src = (const int*)d_in[2];
  const int* dst = (const int*)d_in[3];
  const float* Wm1 = (const float*)d_in[4];
  const float* bm1 = (const float*)d_in[5];
  const float* Wa1 = (const float*)d_in[6];
  const float* ba1 = (const float*)d_in[7];
  const float* Wm2 = (const float*)d_in[8];
  const float* bm2 = (const float*)d_in[9];
  const float* Wa2 = (const float*)d_in[10];
  const float* ba2 = (const float*)d_in[11];
  const float* Wm3 = (const float*)d_in[12];
  const float* bm3 = (const float*)d_in[13];
  const float* Wa3 = (const float*)d_in[14];
  const float* ba3 = (const float*)d_in[15];
  const float* Wp = (const float*)d_in[16];
  const float* bp = (const float*)d_in[17];
  float* out = (float*)d_out;

  char* base = (char*)d_ws;
  size_t woff = 0;
  auto alloc = [&](size_t bytes) -> void* {
    void* p = base + woff;
    woff += (bytes + 255) & ~(size_t)255;
    return p;
  };
  int* cnt = (int*)alloc((size_t)2 * NN * 4);
  int* fill = cnt + NN;
  int* offs = (int*)alloc((size_t)(NN + 1) * 4);
  int* ce = (int*)alloc((size_t)NE * 4);
  int* cs = (int*)alloc((size_t)NE * 4);
  float* deg = (float*)alloc((size_t)NN * 4);
  auto aplane = [&](int w) { return (ushort*)alloc((size_t)NN * w * 2); };
  ushort* nfh = aplane(128); ushort* nfl = aplane(128);
  ushort* eah = aplane(128); ushort* eal = aplane(128);
  ushort* h1h = aplane(160); ushort* h1l = aplane(160);
  ushort* h2h = aplane(160); ushort* h2l = aplane(160);
  ushort* nmh = aplane(160); ushort* nml = aplane(160);
  ushort* ph = aplane(160);
  float* pe1 = (float*)alloc((size_t)NN * 160 * 4);
  float* pe2 = (float*)alloc((size_t)NN * 160 * 4);
  float* pe3 = (float*)alloc((size_t)NN * 128 * 4);
  float* hsd = (float*)alloc((size_t)NN * 32 * 4);
  auto wpk = [&](int kt, int ng) { return (ushort*)alloc((size_t)kt * ng * 512 * 2); };
  ushort* Wm1h = wpk(8, 10);  ushort* Wm1l = wpk(8, 10);
  ushort* Wa1h = wpk(9, 10);  ushort* Wa1l = wpk(9, 10);
  ushort* Wm2h = wpk(9, 10);  ushort* Wm2l = wpk(9, 10);
  ushort* Wa2h = wpk(10, 10); ushort* Wa2l = wpk(10, 10);
  ushort* Wm3h = wpk(9, 8);   ushort* Wm3l = wpk(9, 8);
  ushort* Wa3h = wpk(9, 8);   ushort* Wa3l = wpk(9, 8);
  ushort* Wpph = wpk(4, 2);   ushort* Wppl = wpk(4, 2);

  hipMemsetAsync(cnt, 0, (size_t)2 * NN * 4, stream);

  // CSR build
  k_hist<<<cdiv(NE, 256), 256, 0, stream>>>(dst, cnt);
  k_scan<<<1, 1024, 0, stream>>>(cnt, offs);
  k_scatter<<<cdiv(NE, 256), 256, 0, stream>>>(src, dst, offs, fill, ce, cs);

  // prep: 7 weight packs + nf conversion in one dispatch
  PrepArgs pa;
  pa.d[0] = {Wm1, Wm1h, Wm1l, 152, 128, 128, 128, 256, 10, 8, 0};
  pa.d[1] = {Wa1, Wa1h, Wa1l, 152, 128, 128, 152, 280, 10, 9, 0};
  pa.d[2] = {Wm2, Wm2h, Wm2l, 152, 152, 160, 128, 280, 10, 9, 0};
  pa.d[3] = {Wa2, Wa2h, Wa2l, 152, 152, 160, 152, 304, 10, 10, 0};
  pa.d[4] = {Wm3, Wm3h, Wm3l, 128, 152, 160, 128, 280, 8, 9, 0};
  pa.d[5] = {Wa3, Wa3h, Wa3l, 128, 152, 160, 128, 280, 8, 9, 0};
  pa.d[6] = {Wp, Wpph, Wppl, 32, 128, 128, 0, 256, 2, 4, 1};
  pa.nf = nfeats; pa.nfh = nfh; pa.nfl = nfl;
  k_prep<<<dim3(128, 8), 256, 0, stream>>>(pa);

  // eagg + deg (the 164 MB HBM stream)
  k_eagg<<<NN, 64, 0, stream>>>(efeats, ce, offs, eah, eal, deg);

  // proj1 + pe1/pe2/pe3 (one dispatch; pe W pointers offset to e-part tiles)
  k_projpe<<<dim3(19, MTB), 64, 0, stream>>>(
      nfh, nfl, eah, eal, Wm1h, Wm1l,
      Wm1h + (size_t)4 * 10 * 512, Wm1l + (size_t)4 * 10 * 512,
      Wm2h + (size_t)5 * 10 * 512, Wm2l + (size_t)5 * 10 * 512,
      Wm3h + (size_t)5 * 8 * 512, Wm3l + (size_t)5 * 8 * 512,
      bm1, bm2, bm3, deg, ph, pe1, pe2, pe3);

  // layer 1: gather -> apply1+proj2
  k_gath<160><<<NN, 64, 0, stream>>>(ph, pe1, deg, cs, offs, nmh, nml);
  k_applyproj<4, 5, 10, 10, false><<<MTB, 320, 0, stream>>>(
      nfh, nfl, nmh, nml, Wa1h, Wa1l, ba1, h1h, h1l, Wm2h, Wm2l, ph, nullptr, 152, 152);
  // layer 2
  k_gath<160><<<NN, 64, 0, stream>>>(ph, pe2, deg, cs, offs, nmh, nml);
  k_applyproj<5, 5, 10, 8, false><<<MTB, 320, 0, stream>>>(
      h1h, h1l, nmh, nml, Wa2h, Wa2l, ba2, h2h, h2l, Wm3h, Wm3l, ph, nullptr, 152, 128);
  // layer 3: apply3 + edge predictor (h3 never hits global)
  k_gath<128><<<NN, 64, 0, stream>>>(ph, pe3, deg, cs, offs, nmh, nml);
  k_applyproj<5, 4, 8, 2, true><<<MTB, 256, 0, stream>>>(
      h2h, h2l, nmh, nml, Wa3h, Wa3l, ba3, nullptr, nullptr, Wpph, Wppl, nullptr, hsd, 128, 32);

  k_edge_out<<<cdiv(NE * 15, 256), 256, 0, stream>>>(src, dst, hsd, bp, out);
}